// Round 3
// baseline (927.852 us; speedup 1.0000x reference)
//
#include <hip/hip_runtime.h>
#include <cstdint>
#include <cstddef>

// GraphMambaLayer on MI355X.
// Key insight: _ssm / merge are strictly per-token, so the order/rv gather-scatter
// and the flips cancel exactly -> drop argsort entirely. All matmuls run as
// bf16 MFMA (16x16x32) with f32 accumulate; weights are transposed to [N][K]
// bf16 once per call (piw columns interleaved in 16-wide z/gate groups so the
// silu(z)*sigmoid(gate) epilogue pairs fragments within a lane).

typedef unsigned short u16;
typedef __bf16 bf16x8 __attribute__((ext_vector_type(8)));
typedef float f32x4 __attribute__((ext_vector_type(4)));

#define MROWS 8192

__device__ __forceinline__ u16 f2bf(float f){
  unsigned u = __float_as_uint(f);
  u += 0x7FFFu + ((u >> 16) & 1u);           // RNE
  return (u16)(u >> 16);
}

__device__ __forceinline__ float wred64(float v){
#pragma unroll
  for (int o = 32; o > 0; o >>= 1) v += __shfl_xor(v, o, 64);
  return v;
}

#define GLD16(gp, lp) __builtin_amdgcn_global_load_lds( \
    (const __attribute__((address_space(1))) unsigned int*)(gp), \
    (__attribute__((address_space(3))) unsigned int*)(lp), 16, 0, 0)

// ---------------- weight transpose + bf16 convert ----------------------------
// in: f32 [R][C] row-major.  out: bf16 [C][Kpad] = in^T (K zero-padded).
// zgate: output row n maps to orig col (slot<16 ? 16g+slot : C/2+16g+slot-16),
// g=n>>5, slot=n&31  -> z/gate interleaved in 16-wide groups.
__global__ __launch_bounds__(256) void transpose_w(
    const float* __restrict__ in, u16* __restrict__ out,
    int R, int C, int Kpad, int zgate){
  __shared__ float tile[32][33];
  int n0 = blockIdx.x << 5, k0 = blockIdx.y << 5;
  int tx = threadIdx.x & 31, ty = threadIdx.x >> 5;
#pragma unroll
  for (int i = 0; i < 32; i += 8){
    int k = k0 + ty + i, n = n0 + tx;
    int oc = n;
    if (zgate){ int g = n >> 5, sl = n & 31;
      oc = (sl < 16) ? (g << 4) + sl : (C >> 1) + (g << 4) + sl - 16; }
    tile[ty + i][tx] = (k < R) ? in[(size_t)k * C + oc] : 0.f;
  }
  __syncthreads();
#pragma unroll
  for (int i = 0; i < 32; i += 8){
    int n = n0 + ty + i, k = k0 + tx;
    out[(size_t)n * Kpad + k] = f2bf(tile[tx][ty + i]);
  }
}

__global__ __launch_bounds__(256) void perm_bias(
    const float* __restrict__ in, float* __restrict__ out){
  int n = blockIdx.x * 256 + threadIdx.x;
  int g = n >> 5, sl = n & 31;
  out[n] = in[(sl < 16) ? (g << 4) + sl : 1024 + (g << 4) + sl - 16];
}

// ---------------- attn_maps moments -> sinusoidal encoding -------------------
// One block per (b,k) row: 5 weighted sums in one pass over 4096 floats, then
// enc row [192] bf16: [sin(cy*f) cos(cy*f) sin(cx*f) cos(cx*f) spread 0-pad].
__global__ __launch_bounds__(256) void stats_enc(
    const float* __restrict__ attn, u16* __restrict__ enc){
  int row = blockIdx.x;
  const float4* a4 = (const float4*)(attn + (size_t)row * 4096);
  int t = threadIdx.x;
  const float inv63 = 1.0f / 63.0f;
  float s0 = 0, sy = 0, sx = 0, sy2 = 0, sx2 = 0;
#pragma unroll
  for (int i = 0; i < 4; ++i){
    int c = t + 256 * i;
    float4 v = a4[c];
    int n = 4 * c;
#pragma unroll
    for (int e = 0; e < 4; ++e){
      float av = (&v.x)[e];
      int nn = n + e;
      float gy = (float)(nn >> 6) * inv63;
      float gx = (float)(nn & 63) * inv63;
      s0 += av; sy += av * gy; sx += av * gx;
      sy2 += av * gy * gy; sx2 += av * gx * gx;
    }
  }
  s0 = wred64(s0); sy = wred64(sy); sx = wred64(sx);
  sy2 = wred64(sy2); sx2 = wred64(sx2);
  __shared__ float red[4][5];
  __shared__ float outv[3];
  int wv = t >> 6, lane = t & 63;
  if (lane == 0){ red[wv][0]=s0; red[wv][1]=sy; red[wv][2]=sx; red[wv][3]=sy2; red[wv][4]=sx2; }
  __syncthreads();
  if (t == 0){
    float S=0, Ay=0, Ax=0, Ay2=0, Ax2=0;
    for (int w = 0; w < 4; ++w){ S+=red[w][0]; Ay+=red[w][1]; Ax+=red[w][2]; Ay2+=red[w][3]; Ax2+=red[w][4]; }
    float denom = S + 1e-8f;
    float cy = Ay / denom, cx = Ax / denom;
    float sp2 = (Ay2 - 2.f*cy*Ay + cy*cy*S + Ax2 - 2.f*cx*Ax + cx*cx*S) / denom;
    outv[0] = cy; outv[1] = cx; outv[2] = sqrtf(fmaxf(sp2, 0.f));
  }
  __syncthreads();
  if (t < 192){
    float cy = outv[0], cx = outv[1];
    float val = 0.f;
    if (t < 128){
      int j = t & 31;
      float fr = expf(-0.28782313662425572f * (float)j);   // ln(10000)/32
      float base = (t < 64) ? cy : cx;
      float ang = base * fr;
      val = ((t >> 5) & 1) ? cosf(ang) : sinf(ang);
    } else if (t == 128) val = outv[2];
    enc[(size_t)row * 192 + t] = f2bf(val);
  }
}

// ---------------- LayerNorm kernels (1 wave / row) ---------------------------
__global__ __launch_bounds__(256) void ln_dual(
    const float* __restrict__ x,
    const float* __restrict__ g1, const float* __restrict__ b1,
    const float* __restrict__ g2, const float* __restrict__ b2,
    u16* __restrict__ o1, u16* __restrict__ o2){
  int row = blockIdx.x * 4 + (threadIdx.x >> 6);
  int lane = threadIdx.x & 63, c = lane * 8;
  const float* xr = x + (size_t)row * 512 + c;
  float v[8];
  *(float4*)(v) = *(const float4*)(xr); *(float4*)(v+4) = *(const float4*)(xr+4);
  float s = 0.f;
#pragma unroll
  for (int j = 0; j < 8; ++j) s += v[j];
  float m = wred64(s) * (1.f/512.f);
  float q = 0.f;
#pragma unroll
  for (int j = 0; j < 8; ++j){ float d = v[j]-m; q += d*d; }
  float rstd = rsqrtf(wred64(q)*(1.f/512.f) + 1e-5f);
  float G1[8],B1[8],G2[8],B2[8];
  *(float4*)(G1)=*(const float4*)(g1+c); *(float4*)(G1+4)=*(const float4*)(g1+c+4);
  *(float4*)(B1)=*(const float4*)(b1+c); *(float4*)(B1+4)=*(const float4*)(b1+c+4);
  *(float4*)(G2)=*(const float4*)(g2+c); *(float4*)(G2+4)=*(const float4*)(g2+c+4);
  *(float4*)(B2)=*(const float4*)(b2+c); *(float4*)(B2+4)=*(const float4*)(b2+c+4);
  u16 u1[8] __attribute__((aligned(16)));
  u16 u2[8] __attribute__((aligned(16)));
#pragma unroll
  for (int j = 0; j < 8; ++j){
    float nv = (v[j]-m)*rstd;
    u1[j] = f2bf(nv*G1[j]+B1[j]);
    u2[j] = f2bf(nv*G2[j]+B2[j]);
  }
  *(uint4*)(o1 + (size_t)row*512 + c) = *(const uint4*)u1;
  *(uint4*)(o2 + (size_t)row*512 + c) = *(const uint4*)u2;
}

__global__ __launch_bounds__(256) void ln1024(
    const float* __restrict__ x, const float* __restrict__ g,
    const float* __restrict__ b, u16* __restrict__ o){
  int row = blockIdx.x * 4 + (threadIdx.x >> 6);
  int lane = threadIdx.x & 63, c = lane * 16;
  const float* xr = x + (size_t)row * 1024 + c;
  float v[16];
#pragma unroll
  for (int i = 0; i < 4; ++i) *(float4*)(v + 4*i) = *(const float4*)(xr + 4*i);
  float s = 0.f;
#pragma unroll
  for (int j = 0; j < 16; ++j) s += v[j];
  float m = wred64(s) * (1.f/1024.f);
  float q = 0.f;
#pragma unroll
  for (int j = 0; j < 16; ++j){ float d = v[j]-m; q += d*d; }
  float rstd = rsqrtf(wred64(q)*(1.f/1024.f) + 1e-5f);
  float G[16], B[16];
#pragma unroll
  for (int i = 0; i < 4; ++i){
    *(float4*)(G + 4*i) = *(const float4*)(g + c + 4*i);
    *(float4*)(B + 4*i) = *(const float4*)(b + c + 4*i);
  }
  u16 u[16] __attribute__((aligned(16)));
#pragma unroll
  for (int j = 0; j < 16; ++j) u[j] = f2bf((v[j]-m)*rstd*G[j] + B[j]);
  *(uint4*)(o + (size_t)row*1024 + c)     = *(const uint4*)(u);
  *(uint4*)(o + (size_t)row*1024 + c + 8) = *(const uint4*)(u + 8);
}

// r2 -> s1 = LN(r2; ng,nb) (f32), h2 = LN(s1; fg,fb) (bf16)
__global__ __launch_bounds__(256) void ln_double(
    const float* __restrict__ x,
    const float* __restrict__ ng, const float* __restrict__ nb,
    const float* __restrict__ fg, const float* __restrict__ fbv,
    float* __restrict__ s1, u16* __restrict__ h2){
  int row = blockIdx.x * 4 + (threadIdx.x >> 6);
  int lane = threadIdx.x & 63, c = lane * 8;
  const float* xr = x + (size_t)row * 512 + c;
  float v[8];
  *(float4*)(v) = *(const float4*)(xr); *(float4*)(v+4) = *(const float4*)(xr+4);
  float s = 0.f;
#pragma unroll
  for (int j = 0; j < 8; ++j) s += v[j];
  float m = wred64(s) * (1.f/512.f);
  float q = 0.f;
#pragma unroll
  for (int j = 0; j < 8; ++j){ float d = v[j]-m; q += d*d; }
  float rstd = rsqrtf(wred64(q)*(1.f/512.f) + 1e-5f);
  float NG[8],NB[8],FG[8],FB[8];
  *(float4*)(NG)=*(const float4*)(ng+c); *(float4*)(NG+4)=*(const float4*)(ng+c+4);
  *(float4*)(NB)=*(const float4*)(nb+c); *(float4*)(NB+4)=*(const float4*)(nb+c+4);
  *(float4*)(FG)=*(const float4*)(fg+c); *(float4*)(FG+4)=*(const float4*)(fg+c+4);
  *(float4*)(FB)=*(const float4*)(fbv+c);*(float4*)(FB+4)=*(const float4*)(fbv+c+4);
  float w[8];
#pragma unroll
  for (int j = 0; j < 8; ++j) w[j] = (v[j]-m)*rstd*NG[j] + NB[j];
  *(float4*)(s1 + (size_t)row*512 + c)   = *(const float4*)(w);
  *(float4*)(s1 + (size_t)row*512 + c+4) = *(const float4*)(w+4);
  float s2 = 0.f;
#pragma unroll
  for (int j = 0; j < 8; ++j) s2 += w[j];
  float m2 = wred64(s2) * (1.f/512.f);
  float q2 = 0.f;
#pragma unroll
  for (int j = 0; j < 8; ++j){ float d = w[j]-m2; q2 += d*d; }
  float rstd2 = rsqrtf(wred64(q2)*(1.f/512.f) + 1e-5f);
  u16 u[8] __attribute__((aligned(16)));
#pragma unroll
  for (int j = 0; j < 8; ++j) u[j] = f2bf((w[j]-m2)*rstd2*FG[j] + FB[j]);
  *(uint4*)(h2 + (size_t)row*512 + c) = *(const uint4*)u;
}

// ---------------- bf16 MFMA GEMM, A[M,K] x BT[N,K]^T, fused epilogues --------
// EPI 0: bf16 out = gelu(v+bias)              (ldo = N)
// EPI 1: f32 out = v+bias+res                 (ldo = N)
// EPI 2: f32 out = (v+bias+res)*km[row]       (ldo = N)
// EPI 3: f32 out[N/2] = silu(z)*sigmoid(g), z/gate in alternating 16-col groups
// EPI 4: bf16 out[row*ldo+coloff+col] = v+bias+res (res stride N)
template<int EPI>
__global__ __launch_bounds__(256, 2) void gemm_bt(
    const u16* __restrict__ A, const u16* __restrict__ BT,
    const float* __restrict__ bias, const float* __restrict__ res,
    float* __restrict__ outF, u16* __restrict__ outB,
    const float* __restrict__ km,
    int K, int N, int ldo, int coloff){
  __shared__ u16 Asm[128 * 64];
  __shared__ u16 Bsm[128 * 64];
  const int tid = threadIdx.x, wv = tid >> 6, lane = tid & 63;
  const int m0 = blockIdx.y << 7, n0 = blockIdx.x << 7;
  const int wr = wv >> 1, wc = wv & 1;

  // staging: linear LDS dest, pre-swizzled global source (byte ^= (row&7)<<4)
  const int rload = (wv << 5) + (lane >> 3);
  const int ksrc = ((16 * (lane & 7)) ^ (((lane >> 3) & 7) << 4)) >> 1;
  const u16* gA = A + (size_t)(m0 + rload) * K + ksrc;
  const u16* gB = BT + (size_t)(n0 + rload) * K + ksrc;
  u16* ldsA = Asm + (wv << 11);
  u16* ldsB = Bsm + (wv << 11);

  f32x4 acc[4][4] = {};
  const int cbase = 16 * (lane >> 4);
  const int swz = (lane & 7) << 4;

  for (int kt = 0; kt < K; kt += 64){
#pragma unroll
    for (int it = 0; it < 4; ++it){
      GLD16(gA + (size_t)it * 8 * K + kt, ldsA + it * 512);
      GLD16(gB + (size_t)it * 8 * K + kt, ldsB + it * 512);
    }
    __syncthreads();
#pragma unroll
    for (int ks = 0; ks < 64; ks += 32){
      const int cs = ((2 * ks + cbase) ^ swz) >> 1;
      bf16x8 af[4], bfr[4];
#pragma unroll
      for (int m = 0; m < 4; ++m)
        af[m] = *reinterpret_cast<const bf16x8*>(&Asm[(wr*64 + m*16 + (lane & 15)) * 64 + cs]);
#pragma unroll
      for (int n = 0; n < 4; ++n)
        bfr[n] = *reinterpret_cast<const bf16x8*>(&Bsm[(wc*64 + n*16 + (lane & 15)) * 64 + cs]);
#pragma unroll
      for (int m = 0; m < 4; ++m)
#pragma unroll
        for (int n = 0; n < 4; ++n)
          acc[m][n] = __builtin_amdgcn_mfma_f32_16x16x32_bf16(af[m], bfr[n], acc[m][n], 0, 0, 0);
    }
    __syncthreads();
  }

  const int lr = (lane >> 4) << 2, lc = lane & 15;
#pragma unroll
  for (int m = 0; m < 4; ++m){
    const int grow0 = m0 + wr * 64 + m * 16 + lr;
    if constexpr (EPI == 3){
#pragma unroll
      for (int n = 0; n < 4; n += 2){
        const int zc = n0 + wc * 64 + n * 16 + lc;
        const float bz = bias[zc], bg = bias[zc + 16];
        const int ucol = ((n0 + wc * 64) >> 1) + (n << 3) + lc;
#pragma unroll
        for (int r = 0; r < 4; ++r){
          float z = acc[m][n][r] + bz;
          float g = acc[m][n + 1][r] + bg;
          outF[(size_t)(grow0 + r) * ldo + ucol] =
              (z / (1.f + expf(-z))) * (1.f / (1.f + expf(-g)));
        }
      }
    } else {
#pragma unroll
      for (int n = 0; n < 4; ++n){
        const int col = n0 + wc * 64 + n * 16 + lc;
        const float bv = bias[col];
#pragma unroll
        for (int r = 0; r < 4; ++r){
          const int grow = grow0 + r;
          float v = acc[m][n][r] + bv;
          if constexpr (EPI == 0){
            outB[(size_t)grow * ldo + col] = f2bf(0.5f * v * (1.f + erff(v * 0.70710678118654752f)));
          } else if constexpr (EPI == 1){
            outF[(size_t)grow * ldo + col] = v + res[(size_t)grow * N + col];
          } else if constexpr (EPI == 2){
            outF[(size_t)grow * ldo + col] = (v + res[(size_t)grow * N + col]) * km[grow];
          } else {
            outB[(size_t)grow * ldo + coloff + col] = f2bf(v + res[(size_t)grow * N + col]);
          }
        }
      }
    }
  }
}

// -----------------------------------------------------------------------------
extern "C" void kernel_launch(void* const* d_in, const int* in_sizes, int n_in,
                              void* d_out, int out_size, void* d_ws, size_t ws_size,
                              hipStream_t stream){
  (void)in_sizes; (void)n_in; (void)out_size; (void)ws_size;
  const float* s_in   = (const float*)d_in[0];
  const float* attn   = (const float*)d_in[1];
  const float* km     = (const float*)d_in[2];
  const float* se_w1  = (const float*)d_in[3];
  const float* se_b1  = (const float*)d_in[4];
  const float* se_w2  = (const float*)d_in[5];
  const float* se_b2  = (const float*)d_in[6];
  const float* png[2] = {(const float*)d_in[7],  (const float*)d_in[15]};
  const float* pnb[2] = {(const float*)d_in[8],  (const float*)d_in[16]};
  const float* ppiw[2]= {(const float*)d_in[9],  (const float*)d_in[17]};
  const float* ppib[2]= {(const float*)d_in[10], (const float*)d_in[18]};
  const float* ppow[2]= {(const float*)d_in[11], (const float*)d_in[19]};
  const float* ppob[2]= {(const float*)d_in[12], (const float*)d_in[20]};
  const float* pig[2] = {(const float*)d_in[13], (const float*)d_in[21]};
  const float* pibt[2]= {(const float*)d_in[14], (const float*)d_in[22]};
  const float* mrg_w  = (const float*)d_in[23];
  const float* mrg_b  = (const float*)d_in[24];
  const float* nrm_g  = (const float*)d_in[25];
  const float* nrm_b  = (const float*)d_in[26];
  const float* ffn_ng = (const float*)d_in[27];
  const float* ffn_nb = (const float*)d_in[28];
  const float* ffn_w1 = (const float*)d_in[29];
  const float* ffn_b1 = (const float*)d_in[30];
  const float* ffn_w2 = (const float*)d_in[31];
  const float* ffn_b2 = (const float*)d_in[32];
  float* out = (float*)d_out;

  char* ws = (char*)d_ws;
  size_t off = 0;
  auto alloc = [&](size_t bytes)->char*{
    char* p = ws + off; off += (bytes + 255) & ~(size_t)255; return p; };

  // bf16 transposed weights
  u16* w_sew1 = (u16*)alloc(512 * 192 * 2);
  u16* w_sew2 = (u16*)alloc(512 * 512 * 2);
  u16* w_piw[2][2]; u16* w_pow[2][2]; float* pibp[2][2];
  for (int d = 0; d < 2; ++d)
    for (int i = 0; i < 2; ++i){
      w_piw[d][i] = (u16*)alloc(2048 * 512 * 2);
      w_pow[d][i] = (u16*)alloc(512 * 1024 * 2);
      pibp[d][i]  = (float*)alloc(2048 * 4);
    }
  u16* w_mrg[2]; u16* w_ffn1[2]; u16* w_ffn2[2];
  for (int i = 0; i < 2; ++i){
    w_mrg[i]  = (u16*)alloc(512 * 1024 * 2);
    w_ffn1[i] = (u16*)alloc(2048 * 512 * 2);
    w_ffn2[i] = (u16*)alloc(512 * 2048 * 2);
  }
  // activations
  u16*   enc  = (u16*)alloc((size_t)MROWS * 192 * 2);
  u16*   t1h2 = (u16*)alloc((size_t)MROWS * 512 * 2);   // t1, later h2
  float* sc   = (float*)alloc((size_t)MROWS * 512 * 4); // running state
  u16*   hf   = (u16*)alloc((size_t)MROWS * 512 * 2);
  u16*   hb   = (u16*)alloc((size_t)MROWS * 512 * 2);
  char*  big  = alloc((size_t)MROWS * 1024 * 4);        // upre / r2 / t2 alias
  float* upre = (float*)big;
  float* r2   = (float*)big;
  u16*   t2   = (u16*)big;
  u16*   ubf  = (u16*)alloc((size_t)MROWS * 1024 * 2);
  u16*   fbuf = (u16*)alloc((size_t)MROWS * 1024 * 2);
  float* s1   = (float*)alloc((size_t)MROWS * 512 * 4);

  // ---- weight conversion (transpose + bf16, zgate interleave for piw) ----
  transpose_w<<<dim3(16, 6),  256, 0, stream>>>(se_w1, w_sew1, 129, 512, 192, 0);
  transpose_w<<<dim3(16, 16), 256, 0, stream>>>(se_w2, w_sew2, 512, 512, 512, 0);
  for (int d = 0; d < 2; ++d)
    for (int i = 0; i < 2; ++i){
      transpose_w<<<dim3(64, 16), 256, 0, stream>>>(ppiw[d] + (size_t)i*512*2048, w_piw[d][i], 512, 2048, 512, 1);
      transpose_w<<<dim3(16, 32), 256, 0, stream>>>(ppow[d] + (size_t)i*1024*512, w_pow[d][i], 1024, 512, 1024, 0);
      perm_bias<<<8, 256, 0, stream>>>(ppib[d] + (size_t)i*2048, pibp[d][i]);
    }
  for (int i = 0; i < 2; ++i){
    transpose_w<<<dim3(16, 32), 256, 0, stream>>>(mrg_w  + (size_t)i*1024*512, w_mrg[i],  1024, 512, 1024, 0);
    transpose_w<<<dim3(64, 16), 256, 0, stream>>>(ffn_w1 + (size_t)i*512*2048, w_ffn1[i], 512, 2048, 512, 0);
    transpose_w<<<dim3(16, 64), 256, 0, stream>>>(ffn_w2 + (size_t)i*2048*512, w_ffn2[i], 2048, 512, 2048, 0);
  }

  // ---- spatial encoding ----
  stats_enc<<<MROWS, 256, 0, stream>>>(attn, enc);
  // s += gelu(enc@W1+b1)@W2 + b2
  gemm_bt<0><<<dim3(4, 64), 256, 0, stream>>>(enc,  w_sew1, se_b1, nullptr, nullptr, t1h2, nullptr, 192, 512, 512, 0);
  gemm_bt<1><<<dim3(4, 64), 256, 0, stream>>>(t1h2, w_sew2, se_b2, s_in,    sc,      nullptr, nullptr, 512, 512, 512, 0);

  // ---- layers (order/rv/flip cancel: all per-token) ----
  for (int i = 0; i < 2; ++i){
    ln_dual<<<MROWS/4, 256, 0, stream>>>(sc, png[0]+i*512, pnb[0]+i*512,
                                         png[1]+i*512, pnb[1]+i*512, hf, hb);
    for (int d = 0; d < 2; ++d){
      const u16* h = d ? hb : hf;
      gemm_bt<3><<<dim3(16, 64), 256, 0, stream>>>(h, w_piw[d][i], pibp[d][i],
          nullptr, upre, nullptr, nullptr, 512, 2048, 1024, 0);
      ln1024<<<MROWS/4, 256, 0, stream>>>(upre, pig[d]+i*1024, pibt[d]+i*1024, ubf);
      gemm_bt<4><<<dim3(4, 64), 256, 0, stream>>>(ubf, w_pow[d][i], ppob[d]+i*512,
          sc, nullptr, fbuf, nullptr, 1024, 512, 1024, d*512);
    }
    gemm_bt<1><<<dim3(4, 64), 256, 0, stream>>>(fbuf, w_mrg[i], mrg_b+i*512,
        sc, r2, nullptr, nullptr, 1024, 512, 512, 0);
    ln_double<<<MROWS/4, 256, 0, stream>>>(r2, nrm_g+i*512, nrm_b+i*512,
        ffn_ng+i*512, ffn_nb+i*512, s1, t1h2);
    gemm_bt<0><<<dim3(16, 64), 256, 0, stream>>>(t1h2, w_ffn1[i], ffn_b1+i*2048,
        nullptr, nullptr, t2, nullptr, 512, 2048, 2048, 0);
    gemm_bt<2><<<dim3(4, 64), 256, 0, stream>>>(t2, w_ffn2[i], ffn_b2+i*512,
        s1, (i == 1 ? out : sc), nullptr, km, 2048, 512, 512, 0);
  }
}

// Round 4
// 832.195 us; speedup vs baseline: 1.1149x; 1.1149x over previous
//
#include <hip/hip_runtime.h>
#include <cstdint>
#include <cstddef>

// GraphMambaLayer on MI355X.
// R4: BM=64 GEMM variant for N=512 (2-4 blocks/CU vs 1), bf16 u-buffer,
// merged weight-conversion into one descriptor kernel, bias-perm folded
// into EPI3 epilogue. Baseline R3: 928 us, absmax 0.031.

typedef unsigned short u16;
typedef __bf16 bf16x8 __attribute__((ext_vector_type(8)));
typedef float f32x4 __attribute__((ext_vector_type(4)));

#define MROWS 8192

__device__ __forceinline__ u16 f2bf(float f){
  unsigned u = __float_as_uint(f);
  u += 0x7FFFu + ((u >> 16) & 1u);           // RNE
  return (u16)(u >> 16);
}
__device__ __forceinline__ float bf2f(u16 v){
  return __uint_as_float((unsigned)v << 16);
}

__device__ __forceinline__ float wred64(float v){
#pragma unroll
  for (int o = 32; o > 0; o >>= 1) v += __shfl_xor(v, o, 64);
  return v;
}

#define GLD16(gp, lp) __builtin_amdgcn_global_load_lds( \
    (const __attribute__((address_space(1))) unsigned int*)(gp), \
    (__attribute__((address_space(3))) unsigned int*)(lp), 16, 0, 0)

// ---------------- merged weight transpose + bf16 convert ---------------------
// Each descriptor: f32 [R][C] row-major -> bf16 [C][Kpad] = in^T (rows >= R
// zero-filled). zgate: output row n <- orig col (sl<16 ? 16g+sl : C/2+16g+sl-16).
struct TDesc { const float* src; u16* dst; int R, Kpad, C, zgate, nbx, base; };
struct TPack { TDesc d[16]; };

__global__ __launch_bounds__(256) void transpose_all(TPack p){
  int bid = blockIdx.x;
  TDesc dd = p.d[0];
#pragma unroll
  for (int i = 1; i < 16; ++i) if (bid >= p.d[i].base) dd = p.d[i];
  int lb = bid - dd.base;
  int bx = lb % dd.nbx, by = lb / dd.nbx;

  __shared__ float tile[32][33];
  int n0 = bx << 5, k0 = by << 5;
  int tx = threadIdx.x & 31, ty = threadIdx.x >> 5;
#pragma unroll
  for (int i = 0; i < 32; i += 8){
    int k = k0 + ty + i, n = n0 + tx;
    int oc = n;
    if (dd.zgate){ int g = n >> 5, sl = n & 31;
      oc = (sl < 16) ? (g << 4) + sl : (dd.C >> 1) + (g << 4) + sl - 16; }
    tile[ty + i][tx] = (k < dd.R) ? dd.src[(size_t)k * dd.C + oc] : 0.f;
  }
  __syncthreads();
#pragma unroll
  for (int i = 0; i < 32; i += 8){
    int n = n0 + ty + i, k = k0 + tx;
    dd.dst[(size_t)n * dd.Kpad + k] = f2bf(tile[tx][ty + i]);
  }
}

// ---------------- attn_maps moments -> sinusoidal encoding -------------------
__global__ __launch_bounds__(256) void stats_enc(
    const float* __restrict__ attn, u16* __restrict__ enc){
  int row = blockIdx.x;
  const float4* a4 = (const float4*)(attn + (size_t)row * 4096);
  int t = threadIdx.x;
  const float inv63 = 1.0f / 63.0f;
  float s0 = 0, sy = 0, sx = 0, sy2 = 0, sx2 = 0;
#pragma unroll
  for (int i = 0; i < 4; ++i){
    int c = t + 256 * i;
    float4 v = a4[c];
    int n = 4 * c;
#pragma unroll
    for (int e = 0; e < 4; ++e){
      float av = (&v.x)[e];
      int nn = n + e;
      float gy = (float)(nn >> 6) * inv63;
      float gx = (float)(nn & 63) * inv63;
      s0 += av; sy += av * gy; sx += av * gx;
      sy2 += av * gy * gy; sx2 += av * gx * gx;
    }
  }
  s0 = wred64(s0); sy = wred64(sy); sx = wred64(sx);
  sy2 = wred64(sy2); sx2 = wred64(sx2);
  __shared__ float red[4][5];
  __shared__ float outv[3];
  int wv = t >> 6, lane = t & 63;
  if (lane == 0){ red[wv][0]=s0; red[wv][1]=sy; red[wv][2]=sx; red[wv][3]=sy2; red[wv][4]=sx2; }
  __syncthreads();
  if (t == 0){
    float S=0, Ay=0, Ax=0, Ay2=0, Ax2=0;
    for (int w = 0; w < 4; ++w){ S+=red[w][0]; Ay+=red[w][1]; Ax+=red[w][2]; Ay2+=red[w][3]; Ax2+=red[w][4]; }
    float denom = S + 1e-8f;
    float cy = Ay / denom, cx = Ax / denom;
    float sp2 = (Ay2 - 2.f*cy*Ay + cy*cy*S + Ax2 - 2.f*cx*Ax + cx*cx*S) / denom;
    outv[0] = cy; outv[1] = cx; outv[2] = sqrtf(fmaxf(sp2, 0.f));
  }
  __syncthreads();
  if (t < 192){
    float cy = outv[0], cx = outv[1];
    float val = 0.f;
    if (t < 128){
      int j = t & 31;
      float fr = expf(-0.28782313662425572f * (float)j);   // ln(10000)/32
      float base = (t < 64) ? cy : cx;
      float ang = base * fr;
      val = ((t >> 5) & 1) ? cosf(ang) : sinf(ang);
    } else if (t == 128) val = outv[2];
    enc[(size_t)row * 192 + t] = f2bf(val);
  }
}

// ---------------- LayerNorm kernels (1 wave / row) ---------------------------
__global__ __launch_bounds__(256) void ln_dual(
    const float* __restrict__ x,
    const float* __restrict__ g1, const float* __restrict__ b1,
    const float* __restrict__ g2, const float* __restrict__ b2,
    u16* __restrict__ o1, u16* __restrict__ o2){
  int row = blockIdx.x * 4 + (threadIdx.x >> 6);
  int lane = threadIdx.x & 63, c = lane * 8;
  const float* xr = x + (size_t)row * 512 + c;
  float v[8];
  *(float4*)(v) = *(const float4*)(xr); *(float4*)(v+4) = *(const float4*)(xr+4);
  float s = 0.f;
#pragma unroll
  for (int j = 0; j < 8; ++j) s += v[j];
  float m = wred64(s) * (1.f/512.f);
  float q = 0.f;
#pragma unroll
  for (int j = 0; j < 8; ++j){ float d = v[j]-m; q += d*d; }
  float rstd = rsqrtf(wred64(q)*(1.f/512.f) + 1e-5f);
  float G1[8],B1[8],G2[8],B2[8];
  *(float4*)(G1)=*(const float4*)(g1+c); *(float4*)(G1+4)=*(const float4*)(g1+c+4);
  *(float4*)(B1)=*(const float4*)(b1+c); *(float4*)(B1+4)=*(const float4*)(b1+c+4);
  *(float4*)(G2)=*(const float4*)(g2+c); *(float4*)(G2+4)=*(const float4*)(g2+c+4);
  *(float4*)(B2)=*(const float4*)(b2+c); *(float4*)(B2+4)=*(const float4*)(b2+c+4);
  u16 u1[8] __attribute__((aligned(16)));
  u16 u2[8] __attribute__((aligned(16)));
#pragma unroll
  for (int j = 0; j < 8; ++j){
    float nv = (v[j]-m)*rstd;
    u1[j] = f2bf(nv*G1[j]+B1[j]);
    u2[j] = f2bf(nv*G2[j]+B2[j]);
  }
  *(uint4*)(o1 + (size_t)row*512 + c) = *(const uint4*)u1;
  *(uint4*)(o2 + (size_t)row*512 + c) = *(const uint4*)u2;
}

// bf16 in -> bf16 out LN over 1024
__global__ __launch_bounds__(256) void ln1024(
    const u16* __restrict__ x, const float* __restrict__ g,
    const float* __restrict__ b, u16* __restrict__ o){
  int row = blockIdx.x * 4 + (threadIdx.x >> 6);
  int lane = threadIdx.x & 63, c = lane * 16;
  const u16* xr = x + (size_t)row * 1024 + c;
  u16 raw[16] __attribute__((aligned(16)));
  *(uint4*)(raw)     = *(const uint4*)(xr);
  *(uint4*)(raw + 8) = *(const uint4*)(xr + 8);
  float v[16];
#pragma unroll
  for (int j = 0; j < 16; ++j) v[j] = bf2f(raw[j]);
  float s = 0.f;
#pragma unroll
  for (int j = 0; j < 16; ++j) s += v[j];
  float m = wred64(s) * (1.f/1024.f);
  float q = 0.f;
#pragma unroll
  for (int j = 0; j < 16; ++j){ float d = v[j]-m; q += d*d; }
  float rstd = rsqrtf(wred64(q)*(1.f/1024.f) + 1e-5f);
  float G[16], B[16];
#pragma unroll
  for (int i = 0; i < 4; ++i){
    *(float4*)(G + 4*i) = *(const float4*)(g + c + 4*i);
    *(float4*)(B + 4*i) = *(const float4*)(b + c + 4*i);
  }
  u16 u[16] __attribute__((aligned(16)));
#pragma unroll
  for (int j = 0; j < 16; ++j) u[j] = f2bf((v[j]-m)*rstd*G[j] + B[j]);
  *(uint4*)(o + (size_t)row*1024 + c)     = *(const uint4*)(u);
  *(uint4*)(o + (size_t)row*1024 + c + 8) = *(const uint4*)(u + 8);
}

// r2 -> s1 = LN(r2; ng,nb) (f32), h2 = LN(s1; fg,fb) (bf16)
__global__ __launch_bounds__(256) void ln_double(
    const float* __restrict__ x,
    const float* __restrict__ ng, const float* __restrict__ nb,
    const float* __restrict__ fg, const float* __restrict__ fbv,
    float* __restrict__ s1, u16* __restrict__ h2){
  int row = blockIdx.x * 4 + (threadIdx.x >> 6);
  int lane = threadIdx.x & 63, c = lane * 8;
  const float* xr = x + (size_t)row * 512 + c;
  float v[8];
  *(float4*)(v) = *(const float4*)(xr); *(float4*)(v+4) = *(const float4*)(xr+4);
  float s = 0.f;
#pragma unroll
  for (int j = 0; j < 8; ++j) s += v[j];
  float m = wred64(s) * (1.f/512.f);
  float q = 0.f;
#pragma unroll
  for (int j = 0; j < 8; ++j){ float d = v[j]-m; q += d*d; }
  float rstd = rsqrtf(wred64(q)*(1.f/512.f) + 1e-5f);
  float NG[8],NB[8],FG[8],FB[8];
  *(float4*)(NG)=*(const float4*)(ng+c); *(float4*)(NG+4)=*(const float4*)(ng+c+4);
  *(float4*)(NB)=*(const float4*)(nb+c); *(float4*)(NB+4)=*(const float4*)(nb+c+4);
  *(float4*)(FG)=*(const float4*)(fg+c); *(float4*)(FG+4)=*(const float4*)(fg+c+4);
  *(float4*)(FB)=*(const float4*)(fbv+c);*(float4*)(FB+4)=*(const float4*)(fbv+c+4);
  float w[8];
#pragma unroll
  for (int j = 0; j < 8; ++j) w[j] = (v[j]-m)*rstd*NG[j] + NB[j];
  *(float4*)(s1 + (size_t)row*512 + c)   = *(const float4*)(w);
  *(float4*)(s1 + (size_t)row*512 + c+4) = *(const float4*)(w+4);
  float s2 = 0.f;
#pragma unroll
  for (int j = 0; j < 8; ++j) s2 += w[j];
  float m2 = wred64(s2) * (1.f/512.f);
  float q2 = 0.f;
#pragma unroll
  for (int j = 0; j < 8; ++j){ float d = w[j]-m2; q2 += d*d; }
  float rstd2 = rsqrtf(wred64(q2)*(1.f/512.f) + 1e-5f);
  u16 u[8] __attribute__((aligned(16)));
#pragma unroll
  for (int j = 0; j < 8; ++j) u[j] = f2bf((w[j]-m2)*rstd2*FG[j] + FB[j]);
  *(uint4*)(h2 + (size_t)row*512 + c) = *(const uint4*)u;
}

// ---------------- bf16 MFMA GEMM, A[M,K] x BT[N,K]^T, fused epilogues --------
// BM in {64,128}; BN fixed 128; 4 waves (2x2), per-wave (BM/2)x64.
// EPI 0: bf16 out = gelu(v+bias)              (ldo = N)
// EPI 1: f32 out = v+bias+res                 (ldo = N)
// EPI 2: f32 out = (v+bias+res)*km[row]       (ldo = N)
// EPI 3: bf16 out[N/2] = silu(z)*sigmoid(g); z/gate weight rows interleaved in
//        16-wide groups; bias indexed in ORIGINAL layout (z: [0,N/2), g: +N/2)
// EPI 4: bf16 out[row*ldo+coloff+col] = v+bias+res (res stride N)
template<int EPI, int BM>
__global__ __launch_bounds__(256, 2) void gemm_bt(
    const u16* __restrict__ A, const u16* __restrict__ BT,
    const float* __restrict__ bias, const float* __restrict__ res,
    float* __restrict__ outF, u16* __restrict__ outB,
    const float* __restrict__ km,
    int K, int N, int ldo, int coloff){
  constexpr int MR = BM / 32;                 // acc m-fragments per wave
  __shared__ u16 Asm[BM * 64];
  __shared__ u16 Bsm[128 * 64];
  const int tid = threadIdx.x, wv = tid >> 6, lane = tid & 63;
  const int m0 = blockIdx.y * BM, n0 = blockIdx.x << 7;
  const int wr = wv >> 1, wc = wv & 1;

  // staging: linear LDS dest, pre-swizzled global source (byte ^= (row&7)<<4)
  const int rowin = lane >> 3;                               // 0..7
  const int ksrc = ((16 * (lane & 7)) ^ (rowin << 4)) >> 1;  // u16 units
  const int rA = wv * (BM / 4) + rowin;
  const int rB = (wv << 5) + rowin;
  const u16* gA = A + (size_t)(m0 + rA) * K + ksrc;
  const u16* gB = BT + (size_t)(n0 + rB) * K + ksrc;
  u16* ldsA = Asm + wv * (BM / 4) * 64;
  u16* ldsB = Bsm + (wv << 11);

  f32x4 acc[MR][4] = {};
  const int cbase = 16 * (lane >> 4);
  const int swz = (lane & 7) << 4;

  for (int kt = 0; kt < K; kt += 64){
#pragma unroll
    for (int it = 0; it < BM / 32; ++it)
      GLD16(gA + (size_t)it * 8 * K + kt, ldsA + it * 512);
#pragma unroll
    for (int it = 0; it < 4; ++it)
      GLD16(gB + (size_t)it * 8 * K + kt, ldsB + it * 512);
    __syncthreads();
#pragma unroll
    for (int ks = 0; ks < 64; ks += 32){
      const int cs = ((2 * ks + cbase) ^ swz) >> 1;
      bf16x8 af[MR], bfr[4];
#pragma unroll
      for (int m = 0; m < MR; ++m)
        af[m] = *reinterpret_cast<const bf16x8*>(&Asm[(wr*(BM/2) + m*16 + (lane & 15)) * 64 + cs]);
#pragma unroll
      for (int n = 0; n < 4; ++n)
        bfr[n] = *reinterpret_cast<const bf16x8*>(&Bsm[(wc*64 + n*16 + (lane & 15)) * 64 + cs]);
#pragma unroll
      for (int m = 0; m < MR; ++m)
#pragma unroll
        for (int n = 0; n < 4; ++n)
          acc[m][n] = __builtin_amdgcn_mfma_f32_16x16x32_bf16(af[m], bfr[n], acc[m][n], 0, 0, 0);
    }
    __syncthreads();
  }

  const int lr = (lane >> 4) << 2, lc = lane & 15;
#pragma unroll
  for (int m = 0; m < MR; ++m){
    const int grow0 = m0 + wr * (BM/2) + m * 16 + lr;
    if constexpr (EPI == 3){
#pragma unroll
      for (int n = 0; n < 4; n += 2){
        const int zc = n0 + wc * 64 + n * 16 + lc;
        const int bi = ((zc >> 5) << 4) + lc;          // original z-col
        const float bz = bias[bi], bg = bias[(N >> 1) + bi];
        const int ucol = ((n0 + wc * 64) >> 1) + (n << 3) + lc;
#pragma unroll
        for (int r = 0; r < 4; ++r){
          float z = acc[m][n][r] + bz;
          float g = acc[m][n + 1][r] + bg;
          outB[(size_t)(grow0 + r) * ldo + ucol] =
              f2bf((z / (1.f + expf(-z))) * (1.f / (1.f + expf(-g))));
        }
      }
    } else {
#pragma unroll
      for (int n = 0; n < 4; ++n){
        const int col = n0 + wc * 64 + n * 16 + lc;
        const float bv = bias[col];
#pragma unroll
        for (int r = 0; r < 4; ++r){
          const int grow = grow0 + r;
          float v = acc[m][n][r] + bv;
          if constexpr (EPI == 0){
            outB[(size_t)grow * ldo + col] = f2bf(0.5f * v * (1.f + erff(v * 0.70710678118654752f)));
          } else if constexpr (EPI == 1){
            outF[(size_t)grow * ldo + col] = v + res[(size_t)grow * N + col];
          } else if constexpr (EPI == 2){
            outF[(size_t)grow * ldo + col] = (v + res[(size_t)grow * N + col]) * km[grow];
          } else {
            outB[(size_t)grow * ldo + coloff + col] = f2bf(v + res[(size_t)grow * N + col]);
          }
        }
      }
    }
  }
}

// -----------------------------------------------------------------------------
extern "C" void kernel_launch(void* const* d_in, const int* in_sizes, int n_in,
                              void* d_out, int out_size, void* d_ws, size_t ws_size,
                              hipStream_t stream){
  (void)in_sizes; (void)n_in; (void)out_size; (void)ws_size;
  const float* s_in   = (const float*)d_in[0];
  const float* attn   = (const float*)d_in[1];
  const float* km     = (const float*)d_in[2];
  const float* se_w1  = (const float*)d_in[3];
  const float* se_b1  = (const float*)d_in[4];
  const float* se_w2  = (const float*)d_in[5];
  const float* se_b2  = (const float*)d_in[6];
  const float* png[2] = {(const float*)d_in[7],  (const float*)d_in[15]};
  const float* pnb[2] = {(const float*)d_in[8],  (const float*)d_in[16]};
  const float* ppiw[2]= {(const float*)d_in[9],  (const float*)d_in[17]};
  const float* ppib[2]= {(const float*)d_in[10], (const float*)d_in[18]};
  const float* ppow[2]= {(const float*)d_in[11], (const float*)d_in[19]};
  const float* ppob[2]= {(const float*)d_in[12], (const float*)d_in[20]};
  const float* pig[2] = {(const float*)d_in[13], (const float*)d_in[21]};
  const float* pibt[2]= {(const float*)d_in[14], (const float*)d_in[22]};
  const float* mrg_w  = (const float*)d_in[23];
  const float* mrg_b  = (const float*)d_in[24];
  const float* nrm_g  = (const float*)d_in[25];
  const float* nrm_b  = (const float*)d_in[26];
  const float* ffn_ng = (const float*)d_in[27];
  const float* ffn_nb = (const float*)d_in[28];
  const float* ffn_w1 = (const float*)d_in[29];
  const float* ffn_b1 = (const float*)d_in[30];
  const float* ffn_w2 = (const float*)d_in[31];
  const float* ffn_b2 = (const float*)d_in[32];
  float* out = (float*)d_out;

  char* ws = (char*)d_ws;
  size_t off = 0;
  auto alloc = [&](size_t bytes)->char*{
    char* p = ws + off; off += (bytes + 255) & ~(size_t)255; return p; };

  // bf16 transposed weights
  u16* w_sew1 = (u16*)alloc(512 * 192 * 2);
  u16* w_sew2 = (u16*)alloc(512 * 512 * 2);
  u16* w_piw[2][2]; u16* w_pow[2][2];
  for (int d = 0; d < 2; ++d)
    for (int i = 0; i < 2; ++i){
      w_piw[d][i] = (u16*)alloc(2048 * 512 * 2);
      w_pow[d][i] = (u16*)alloc(512 * 1024 * 2);
    }
  u16* w_mrg[2]; u16* w_ffn1[2]; u16* w_ffn2[2];
  for (int i = 0; i < 2; ++i){
    w_mrg[i]  = (u16*)alloc(512 * 1024 * 2);
    w_ffn1[i] = (u16*)alloc(2048 * 512 * 2);
    w_ffn2[i] = (u16*)alloc(512 * 2048 * 2);
  }
  // activations
  u16*   enc  = (u16*)alloc((size_t)MROWS * 192 * 2);
  u16*   t1h2 = (u16*)alloc((size_t)MROWS * 512 * 2);   // t1, later h2
  float* sc   = (float*)alloc((size_t)MROWS * 512 * 4); // running state
  u16*   hf   = (u16*)alloc((size_t)MROWS * 512 * 2);
  u16*   hb   = (u16*)alloc((size_t)MROWS * 512 * 2);
  char*  big  = alloc((size_t)MROWS * 1024 * 4);        // upre(bf16) / r2(f32) / t2(bf16)
  u16*   upre = (u16*)big;
  float* r2   = (float*)big;
  u16*   t2   = (u16*)big;
  u16*   ubf  = (u16*)alloc((size_t)MROWS * 1024 * 2);
  u16*   fbuf = (u16*)alloc((size_t)MROWS * 1024 * 2);
  float* s1   = (float*)alloc((size_t)MROWS * 512 * 4);

  // ---- weight conversion: ONE kernel over 16 descriptors ----
  TPack pk; int base = 0, di = 0;
  auto push = [&](const float* src, u16* dst, int R, int Kpad, int C, int zg){
    TDesc& t = pk.d[di++];
    t.src = src; t.dst = dst; t.R = R; t.Kpad = Kpad; t.C = C; t.zgate = zg;
    t.nbx = C / 32; t.base = base;
    base += (C / 32) * (Kpad / 32);
  };
  push(se_w1, w_sew1, 129, 192, 512, 0);
  push(se_w2, w_sew2, 512, 512, 512, 0);
  for (int d = 0; d < 2; ++d)
    for (int i = 0; i < 2; ++i){
      push(ppiw[d] + (size_t)i*512*2048, w_piw[d][i], 512, 512, 2048, 1);
      push(ppow[d] + (size_t)i*1024*512, w_pow[d][i], 1024, 1024, 512, 0);
    }
  for (int i = 0; i < 2; ++i){
    push(mrg_w  + (size_t)i*1024*512, w_mrg[i],  1024, 1024, 512, 0);
    push(ffn_w1 + (size_t)i*512*2048, w_ffn1[i], 512, 512, 2048, 0);
    push(ffn_w2 + (size_t)i*2048*512, w_ffn2[i], 2048, 2048, 512, 0);
  }
  transpose_all<<<base, 256, 0, stream>>>(pk);

  // ---- spatial encoding ----
  stats_enc<<<MROWS, 256, 0, stream>>>(attn, enc);
  // s += gelu(enc@W1+b1)@W2 + b2
  gemm_bt<0,64><<<dim3(4, 128), 256, 0, stream>>>(enc,  w_sew1, se_b1, nullptr, nullptr, t1h2, nullptr, 192, 512, 512, 0);
  gemm_bt<1,64><<<dim3(4, 128), 256, 0, stream>>>(t1h2, w_sew2, se_b2, s_in,    sc,      nullptr, nullptr, 512, 512, 512, 0);

  // ---- layers (order/rv/flip cancel: all per-token) ----
  for (int i = 0; i < 2; ++i){
    ln_dual<<<MROWS/4, 256, 0, stream>>>(sc, png[0]+i*512, pnb[0]+i*512,
                                         png[1]+i*512, pnb[1]+i*512, hf, hb);
    for (int d = 0; d < 2; ++d){
      const u16* h = d ? hb : hf;
      gemm_bt<3,128><<<dim3(16, 64), 256, 0, stream>>>(h, w_piw[d][i], ppib[d]+(size_t)i*2048,
          nullptr, nullptr, upre, nullptr, 512, 2048, 1024, 0);
      ln1024<<<MROWS/4, 256, 0, stream>>>(upre, pig[d]+i*1024, pibt[d]+i*1024, ubf);
      gemm_bt<4,64><<<dim3(4, 128), 256, 0, stream>>>(ubf, w_pow[d][i], ppob[d]+i*512,
          sc, nullptr, fbuf, nullptr, 1024, 512, 1024, d*512);
    }
    gemm_bt<1,64><<<dim3(4, 128), 256, 0, stream>>>(fbuf, w_mrg[i], mrg_b+i*512,
        sc, r2, nullptr, nullptr, 1024, 512, 512, 0);
    ln_double<<<MROWS/4, 256, 0, stream>>>(r2, nrm_g+i*512, nrm_b+i*512,
        ffn_ng+i*512, ffn_nb+i*512, s1, t1h2);
    gemm_bt<0,128><<<dim3(16, 64), 256, 0, stream>>>(t1h2, w_ffn1[i], ffn_b1+i*2048,
        nullptr, nullptr, t2, nullptr, 512, 2048, 2048, 0);
    gemm_bt<2,64><<<dim3(4, 128), 256, 0, stream>>>(t2, w_ffn2[i], ffn_b2+i*512,
        s1, (i == 1 ? out : sc), nullptr, km, 2048, 512, 512, 0);
  }
}

// Round 5
// 753.906 us; speedup vs baseline: 1.2307x; 1.1038x over previous
//
#include <hip/hip_runtime.h>
#include <cstdint>
#include <cstddef>

// GraphMambaLayer on MI355X.
// R5: f/b direction stacking (piw/pow/ln1024 single dispatches, M=16384),
// BM=64 GEMMs at 4 blocks/CU, bf16 r2/s1 streams.
// R4: 832 us absmax 0.031. R3: 928 us.

typedef unsigned short u16;
typedef __bf16 bf16x8 __attribute__((ext_vector_type(8)));
typedef float f32x4 __attribute__((ext_vector_type(4)));

#define MROWS 8192

__device__ __forceinline__ u16 f2bf(float f){
  unsigned u = __float_as_uint(f);
  u += 0x7FFFu + ((u >> 16) & 1u);           // RNE
  return (u16)(u >> 16);
}
__device__ __forceinline__ float bf2f(u16 v){
  return __uint_as_float((unsigned)v << 16);
}

__device__ __forceinline__ float wred64(float v){
#pragma unroll
  for (int o = 32; o > 0; o >>= 1) v += __shfl_xor(v, o, 64);
  return v;
}

#define GLD16(gp, lp) __builtin_amdgcn_global_load_lds( \
    (const __attribute__((address_space(1))) unsigned int*)(gp), \
    (__attribute__((address_space(3))) unsigned int*)(lp), 16, 0, 0)

// ---------------- merged weight transpose + bf16 convert ---------------------
struct TDesc { const float* src; u16* dst; int R, Kpad, C, zgate, nbx, base; };
struct TPack { TDesc d[16]; };

__global__ __launch_bounds__(256) void transpose_all(TPack p){
  int bid = blockIdx.x;
  TDesc dd = p.d[0];
#pragma unroll
  for (int i = 1; i < 16; ++i) if (bid >= p.d[i].base) dd = p.d[i];
  int lb = bid - dd.base;
  int bx = lb % dd.nbx, by = lb / dd.nbx;

  __shared__ float tile[32][33];
  int n0 = bx << 5, k0 = by << 5;
  int tx = threadIdx.x & 31, ty = threadIdx.x >> 5;
#pragma unroll
  for (int i = 0; i < 32; i += 8){
    int k = k0 + ty + i, n = n0 + tx;
    int oc = n;
    if (dd.zgate){ int g = n >> 5, sl = n & 31;
      oc = (sl < 16) ? (g << 4) + sl : (dd.C >> 1) + (g << 4) + sl - 16; }
    tile[ty + i][tx] = (k < dd.R) ? dd.src[(size_t)k * dd.C + oc] : 0.f;
  }
  __syncthreads();
#pragma unroll
  for (int i = 0; i < 32; i += 8){
    int n = n0 + ty + i, k = k0 + tx;
    dd.dst[(size_t)n * dd.Kpad + k] = f2bf(tile[tx][ty + i]);
  }
}

// ---------------- attn_maps moments -> sinusoidal encoding -------------------
__global__ __launch_bounds__(256) void stats_enc(
    const float* __restrict__ attn, u16* __restrict__ enc){
  int row = blockIdx.x;
  const float4* a4 = (const float4*)(attn + (size_t)row * 4096);
  int t = threadIdx.x;
  const float inv63 = 1.0f / 63.0f;
  float s0 = 0, sy = 0, sx = 0, sy2 = 0, sx2 = 0;
#pragma unroll
  for (int i = 0; i < 4; ++i){
    int c = t + 256 * i;
    float4 v = a4[c];
    int n = 4 * c;
#pragma unroll
    for (int e = 0; e < 4; ++e){
      float av = (&v.x)[e];
      int nn = n + e;
      float gy = (float)(nn >> 6) * inv63;
      float gx = (float)(nn & 63) * inv63;
      s0 += av; sy += av * gy; sx += av * gx;
      sy2 += av * gy * gy; sx2 += av * gx * gx;
    }
  }
  s0 = wred64(s0); sy = wred64(sy); sx = wred64(sx);
  sy2 = wred64(sy2); sx2 = wred64(sx2);
  __shared__ float red[4][5];
  __shared__ float outv[3];
  int wv = t >> 6, lane = t & 63;
  if (lane == 0){ red[wv][0]=s0; red[wv][1]=sy; red[wv][2]=sx; red[wv][3]=sy2; red[wv][4]=sx2; }
  __syncthreads();
  if (t == 0){
    float S=0, Ay=0, Ax=0, Ay2=0, Ax2=0;
    for (int w = 0; w < 4; ++w){ S+=red[w][0]; Ay+=red[w][1]; Ax+=red[w][2]; Ay2+=red[w][3]; Ax2+=red[w][4]; }
    float denom = S + 1e-8f;
    float cy = Ay / denom, cx = Ax / denom;
    float sp2 = (Ay2 - 2.f*cy*Ay + cy*cy*S + Ax2 - 2.f*cx*Ax + cx*cx*S) / denom;
    outv[0] = cy; outv[1] = cx; outv[2] = sqrtf(fmaxf(sp2, 0.f));
  }
  __syncthreads();
  if (t < 192){
    float cy = outv[0], cx = outv[1];
    float val = 0.f;
    if (t < 128){
      int j = t & 31;
      float fr = expf(-0.28782313662425572f * (float)j);   // ln(10000)/32
      float base = (t < 64) ? cy : cx;
      float ang = base * fr;
      val = ((t >> 5) & 1) ? cosf(ang) : sinf(ang);
    } else if (t == 128) val = outv[2];
    enc[(size_t)row * 192 + t] = f2bf(val);
  }
}

// ---------------- LayerNorm kernels (1 wave / row) ---------------------------
// sc(f32) -> hf=LN(g1,b1), hb=LN(g2,b2) both bf16 (adjacent planes of hcat)
__global__ __launch_bounds__(256) void ln_dual(
    const float* __restrict__ x,
    const float* __restrict__ g1, const float* __restrict__ b1,
    const float* __restrict__ g2, const float* __restrict__ b2,
    u16* __restrict__ o1, u16* __restrict__ o2){
  int row = blockIdx.x * 4 + (threadIdx.x >> 6);
  int lane = threadIdx.x & 63, c = lane * 8;
  const float* xr = x + (size_t)row * 512 + c;
  float v[8];
  *(float4*)(v) = *(const float4*)(xr); *(float4*)(v+4) = *(const float4*)(xr+4);
  float s = 0.f;
#pragma unroll
  for (int j = 0; j < 8; ++j) s += v[j];
  float m = wred64(s) * (1.f/512.f);
  float q = 0.f;
#pragma unroll
  for (int j = 0; j < 8; ++j){ float d = v[j]-m; q += d*d; }
  float rstd = rsqrtf(wred64(q)*(1.f/512.f) + 1e-5f);
  float G1[8],B1[8],G2[8],B2[8];
  *(float4*)(G1)=*(const float4*)(g1+c); *(float4*)(G1+4)=*(const float4*)(g1+c+4);
  *(float4*)(B1)=*(const float4*)(b1+c); *(float4*)(B1+4)=*(const float4*)(b1+c+4);
  *(float4*)(G2)=*(const float4*)(g2+c); *(float4*)(G2+4)=*(const float4*)(g2+c+4);
  *(float4*)(B2)=*(const float4*)(b2+c); *(float4*)(B2+4)=*(const float4*)(b2+c+4);
  u16 u1[8] __attribute__((aligned(16)));
  u16 u2[8] __attribute__((aligned(16)));
#pragma unroll
  for (int j = 0; j < 8; ++j){
    float nv = (v[j]-m)*rstd;
    u1[j] = f2bf(nv*G1[j]+B1[j]);
    u2[j] = f2bf(nv*G2[j]+B2[j]);
  }
  *(uint4*)(o1 + (size_t)row*512 + c) = *(const uint4*)u1;
  *(uint4*)(o2 + (size_t)row*512 + c) = *(const uint4*)u2;
}

// bf16 in -> bf16 out LN over 1024; 16384 stacked rows, params per row-half
__global__ __launch_bounds__(256) void ln1024(
    const u16* __restrict__ x,
    const float* __restrict__ gf, const float* __restrict__ bfp,
    const float* __restrict__ gb, const float* __restrict__ bbp,
    u16* __restrict__ o){
  int row = blockIdx.x * 4 + (threadIdx.x >> 6);
  int lane = threadIdx.x & 63, c = lane * 16;
  const float* g = (row >> 13) ? gb : gf;
  const float* b = (row >> 13) ? bbp : bfp;
  const u16* xr = x + (size_t)row * 1024 + c;
  u16 raw[16] __attribute__((aligned(16)));
  *(uint4*)(raw)     = *(const uint4*)(xr);
  *(uint4*)(raw + 8) = *(const uint4*)(xr + 8);
  float v[16];
#pragma unroll
  for (int j = 0; j < 16; ++j) v[j] = bf2f(raw[j]);
  float s = 0.f;
#pragma unroll
  for (int j = 0; j < 16; ++j) s += v[j];
  float m = wred64(s) * (1.f/1024.f);
  float q = 0.f;
#pragma unroll
  for (int j = 0; j < 16; ++j){ float d = v[j]-m; q += d*d; }
  float rstd = rsqrtf(wred64(q)*(1.f/1024.f) + 1e-5f);
  float G[16], B[16];
#pragma unroll
  for (int i = 0; i < 4; ++i){
    *(float4*)(G + 4*i) = *(const float4*)(g + c + 4*i);
    *(float4*)(B + 4*i) = *(const float4*)(b + c + 4*i);
  }
  u16 u[16] __attribute__((aligned(16)));
#pragma unroll
  for (int j = 0; j < 16; ++j) u[j] = f2bf((v[j]-m)*rstd*G[j] + B[j]);
  *(uint4*)(o + (size_t)row*1024 + c)     = *(const uint4*)(u);
  *(uint4*)(o + (size_t)row*1024 + c + 8) = *(const uint4*)(u + 8);
}

// r2(bf16) -> s1 = LN(r2; ng,nb) (bf16), h2 = LN(s1; fg,fb) (bf16)
__global__ __launch_bounds__(256) void ln_double(
    const u16* __restrict__ x,
    const float* __restrict__ ng, const float* __restrict__ nb,
    const float* __restrict__ fg, const float* __restrict__ fbv,
    u16* __restrict__ s1, u16* __restrict__ h2){
  int row = blockIdx.x * 4 + (threadIdx.x >> 6);
  int lane = threadIdx.x & 63, c = lane * 8;
  const u16* xr = x + (size_t)row * 512 + c;
  u16 raw[8] __attribute__((aligned(16)));
  *(uint4*)(raw) = *(const uint4*)(xr);
  float v[8];
#pragma unroll
  for (int j = 0; j < 8; ++j) v[j] = bf2f(raw[j]);
  float s = 0.f;
#pragma unroll
  for (int j = 0; j < 8; ++j) s += v[j];
  float m = wred64(s) * (1.f/512.f);
  float q = 0.f;
#pragma unroll
  for (int j = 0; j < 8; ++j){ float d = v[j]-m; q += d*d; }
  float rstd = rsqrtf(wred64(q)*(1.f/512.f) + 1e-5f);
  float NG[8],NB[8],FG[8],FB[8];
  *(float4*)(NG)=*(const float4*)(ng+c); *(float4*)(NG+4)=*(const float4*)(ng+c+4);
  *(float4*)(NB)=*(const float4*)(nb+c); *(float4*)(NB+4)=*(const float4*)(nb+c+4);
  *(float4*)(FG)=*(const float4*)(fg+c); *(float4*)(FG+4)=*(const float4*)(fg+c+4);
  *(float4*)(FB)=*(const float4*)(fbv+c);*(float4*)(FB+4)=*(const float4*)(fbv+c+4);
  float w[8];
#pragma unroll
  for (int j = 0; j < 8; ++j) w[j] = (v[j]-m)*rstd*NG[j] + NB[j];
  u16 us[8] __attribute__((aligned(16)));
#pragma unroll
  for (int j = 0; j < 8; ++j) us[j] = f2bf(w[j]);
  *(uint4*)(s1 + (size_t)row*512 + c) = *(const uint4*)us;
  float s2 = 0.f;
#pragma unroll
  for (int j = 0; j < 8; ++j) s2 += w[j];
  float m2 = wred64(s2) * (1.f/512.f);
  float q2 = 0.f;
#pragma unroll
  for (int j = 0; j < 8; ++j){ float d = w[j]-m2; q2 += d*d; }
  float rstd2 = rsqrtf(wred64(q2)*(1.f/512.f) + 1e-5f);
  u16 u[8] __attribute__((aligned(16)));
#pragma unroll
  for (int j = 0; j < 8; ++j) u[j] = f2bf((w[j]-m2)*rstd2*FG[j] + FB[j]);
  *(uint4*)(h2 + (size_t)row*512 + c) = *(const uint4*)u;
}

// ---------------- bf16 MFMA GEMM, A[M,K] x BT[N,K]^T, fused epilogues --------
// Stacked-direction support: blocks with m0>=8192 use BT1/bias1 (else BT0/bias0).
// EPI 0: bf16 out = gelu(v+bias)                    (ldo = N)
// EPI 1: f32 out = v+bias+res_f32                   (ldo = N)
// EPI 2: f32 out = (v+bias+res_bf16)*km[row]        (ldo = N)
// EPI 3: bf16 out[N/2] = silu(z)*sigmoid(g); weight rows z/gate-interleaved in
//        16-wide groups; bias in ORIGINAL layout (z: [0,N/2), gate: +N/2)
// EPI 4: bf16 out[(row&8191)*ldo + (row>>13)*512 + col] = v+bias+res_f32
//        (res stride N, row (row&8191))
template<int EPI, int BM>
__global__ __launch_bounds__(256, (BM == 64) ? 4 : 2) void gemm_bt(
    const u16* __restrict__ A,
    const u16* __restrict__ BT0, const u16* __restrict__ BT1,
    const float* __restrict__ bias0, const float* __restrict__ bias1,
    const void* __restrict__ res,
    float* __restrict__ outF, u16* __restrict__ outB,
    const float* __restrict__ km,
    int K, int N, int ldo){
  constexpr int MR = BM / 32;                 // acc m-fragments per wave
  __shared__ u16 Asm[BM * 64];
  __shared__ u16 Bsm[128 * 64];
  const int tid = threadIdx.x, wv = tid >> 6, lane = tid & 63;
  const int m0 = blockIdx.y * BM, n0 = blockIdx.x << 7;
  const int wr = wv >> 1, wc = wv & 1;
  const u16* BT = (m0 < MROWS) ? BT0 : BT1;
  const float* bias = (m0 < MROWS) ? bias0 : bias1;

  // staging: linear LDS dest, pre-swizzled global source (byte ^= (row&7)<<4)
  const int rowin = lane >> 3;                               // 0..7
  const int ksrc = ((16 * (lane & 7)) ^ (rowin << 4)) >> 1;  // u16 units
  const int rA = wv * (BM / 4) + rowin;
  const int rB = (wv << 5) + rowin;
  const u16* gA = A + (size_t)(m0 + rA) * K + ksrc;
  const u16* gB = BT + (size_t)(n0 + rB) * K + ksrc;
  u16* ldsA = Asm + wv * (BM / 4) * 64;
  u16* ldsB = Bsm + (wv << 11);

  f32x4 acc[MR][4] = {};
  const int cbase = 16 * (lane >> 4);
  const int swz = (lane & 7) << 4;

  for (int kt = 0; kt < K; kt += 64){
#pragma unroll
    for (int it = 0; it < BM / 32; ++it)
      GLD16(gA + (size_t)it * 8 * K + kt, ldsA + it * 512);
#pragma unroll
    for (int it = 0; it < 4; ++it)
      GLD16(gB + (size_t)it * 8 * K + kt, ldsB + it * 512);
    __syncthreads();
#pragma unroll
    for (int ks = 0; ks < 64; ks += 32){
      const int cs = ((2 * ks + cbase) ^ swz) >> 1;
      bf16x8 af[MR], bfr[4];
#pragma unroll
      for (int m = 0; m < MR; ++m)
        af[m] = *reinterpret_cast<const bf16x8*>(&Asm[(wr*(BM/2) + m*16 + (lane & 15)) * 64 + cs]);
#pragma unroll
      for (int n = 0; n < 4; ++n)
        bfr[n] = *reinterpret_cast<const bf16x8*>(&Bsm[(wc*64 + n*16 + (lane & 15)) * 64 + cs]);
#pragma unroll
      for (int m = 0; m < MR; ++m)
#pragma unroll
        for (int n = 0; n < 4; ++n)
          acc[m][n] = __builtin_amdgcn_mfma_f32_16x16x32_bf16(af[m], bfr[n], acc[m][n], 0, 0, 0);
    }
    __syncthreads();
  }

  const int lr = (lane >> 4) << 2, lc = lane & 15;
#pragma unroll
  for (int m = 0; m < MR; ++m){
    const int grow0 = m0 + wr * (BM/2) + m * 16 + lr;
    if constexpr (EPI == 3){
#pragma unroll
      for (int n = 0; n < 4; n += 2){
        const int zc = n0 + wc * 64 + n * 16 + lc;
        const int bi = ((zc >> 5) << 4) + lc;          // original z-col
        const float bz = bias[bi], bg = bias[(N >> 1) + bi];
        const int ucol = ((n0 + wc * 64) >> 1) + (n << 3) + lc;
#pragma unroll
        for (int r = 0; r < 4; ++r){
          float z = acc[m][n][r] + bz;
          float g = acc[m][n + 1][r] + bg;
          outB[(size_t)(grow0 + r) * ldo + ucol] =
              f2bf((z / (1.f + expf(-z))) * (1.f / (1.f + expf(-g))));
        }
      }
    } else {
#pragma unroll
      for (int n = 0; n < 4; ++n){
        const int col = n0 + wc * 64 + n * 16 + lc;
        const float bv = bias[col];
#pragma unroll
        for (int r = 0; r < 4; ++r){
          const int grow = grow0 + r;
          float v = acc[m][n][r] + bv;
          if constexpr (EPI == 0){
            outB[(size_t)grow * ldo + col] = f2bf(0.5f * v * (1.f + erff(v * 0.70710678118654752f)));
          } else if constexpr (EPI == 1){
            outF[(size_t)grow * ldo + col] = v + ((const float*)res)[(size_t)grow * N + col];
          } else if constexpr (EPI == 2){
            outF[(size_t)grow * ldo + col] =
                (v + bf2f(((const u16*)res)[(size_t)grow * N + col])) * km[grow];
          } else {  // EPI 4
            const int rowout = grow & (MROWS - 1);
            const int coloff = (grow >> 13) << 9;
            outB[(size_t)rowout * ldo + coloff + col] =
                f2bf(v + ((const float*)res)[(size_t)rowout * N + col]);
          }
        }
      }
    }
  }
}

// -----------------------------------------------------------------------------
extern "C" void kernel_launch(void* const* d_in, const int* in_sizes, int n_in,
                              void* d_out, int out_size, void* d_ws, size_t ws_size,
                              hipStream_t stream){
  (void)in_sizes; (void)n_in; (void)out_size; (void)ws_size;
  const float* s_in   = (const float*)d_in[0];
  const float* attn   = (const float*)d_in[1];
  const float* km     = (const float*)d_in[2];
  const float* se_w1  = (const float*)d_in[3];
  const float* se_b1  = (const float*)d_in[4];
  const float* se_w2  = (const float*)d_in[5];
  const float* se_b2  = (const float*)d_in[6];
  const float* png[2] = {(const float*)d_in[7],  (const float*)d_in[15]};
  const float* pnb[2] = {(const float*)d_in[8],  (const float*)d_in[16]};
  const float* ppiw[2]= {(const float*)d_in[9],  (const float*)d_in[17]};
  const float* ppib[2]= {(const float*)d_in[10], (const float*)d_in[18]};
  const float* ppow[2]= {(const float*)d_in[11], (const float*)d_in[19]};
  const float* ppob[2]= {(const float*)d_in[12], (const float*)d_in[20]};
  const float* pig[2] = {(const float*)d_in[13], (const float*)d_in[21]};
  const float* pibt[2]= {(const float*)d_in[14], (const float*)d_in[22]};
  const float* mrg_w  = (const float*)d_in[23];
  const float* mrg_b  = (const float*)d_in[24];
  const float* nrm_g  = (const float*)d_in[25];
  const float* nrm_b  = (const float*)d_in[26];
  const float* ffn_ng = (const float*)d_in[27];
  const float* ffn_nb = (const float*)d_in[28];
  const float* ffn_w1 = (const float*)d_in[29];
  const float* ffn_b1 = (const float*)d_in[30];
  const float* ffn_w2 = (const float*)d_in[31];
  const float* ffn_b2 = (const float*)d_in[32];
  float* out = (float*)d_out;

  char* ws = (char*)d_ws;
  size_t off = 0;
  auto alloc = [&](size_t bytes)->char*{
    char* p = ws + off; off += (bytes + 255) & ~(size_t)255; return p; };

  // bf16 transposed weights
  u16* w_sew1 = (u16*)alloc(512 * 192 * 2);
  u16* w_sew2 = (u16*)alloc(512 * 512 * 2);
  u16* w_piw[2][2]; u16* w_pow[2][2];
  for (int d = 0; d < 2; ++d)
    for (int i = 0; i < 2; ++i){
      w_piw[d][i] = (u16*)alloc(2048 * 512 * 2);
      w_pow[d][i] = (u16*)alloc(512 * 1024 * 2);
    }
  u16* w_mrg[2]; u16* w_ffn1[2]; u16* w_ffn2[2];
  for (int i = 0; i < 2; ++i){
    w_mrg[i]  = (u16*)alloc(512 * 1024 * 2);
    w_ffn1[i] = (u16*)alloc(2048 * 512 * 2);
    w_ffn2[i] = (u16*)alloc(512 * 2048 * 2);
  }
  // activations
  u16*   enc  = (u16*)alloc((size_t)MROWS * 192 * 2);
  u16*   t1h2 = (u16*)alloc((size_t)MROWS * 512 * 2);    // t1, later h2
  float* sc   = (float*)alloc((size_t)MROWS * 512 * 4);  // running state (f32)
  u16*   hcat = (u16*)alloc((size_t)2 * MROWS * 512 * 2);// [hf; hb]
  char*  big  = alloc((size_t)MROWS * 2048 * 2);         // upre(16384x1024) / r2 / t2
  u16*   upre = (u16*)big;                               // [16384][1024]
  u16*   r2   = (u16*)big;                               // [8192][512]
  u16*   t2   = (u16*)big;                               // [8192][2048]
  u16*   ubf  = (u16*)alloc((size_t)2 * MROWS * 1024 * 2);// [16384][1024]
  u16*   fbuf = (u16*)alloc((size_t)MROWS * 1024 * 2);   // [8192][1024]
  u16*   s1   = (u16*)alloc((size_t)MROWS * 512 * 2);    // bf16 s1

  // ---- weight conversion: ONE kernel over 16 descriptors ----
  TPack pk; int base = 0, di = 0;
  auto push = [&](const float* src, u16* dst, int R, int Kpad, int C, int zg){
    TDesc& t = pk.d[di++];
    t.src = src; t.dst = dst; t.R = R; t.Kpad = Kpad; t.C = C; t.zgate = zg;
    t.nbx = C / 32; t.base = base;
    base += (C / 32) * (Kpad / 32);
  };
  push(se_w1, w_sew1, 129, 192, 512, 0);
  push(se_w2, w_sew2, 512, 512, 512, 0);
  for (int d = 0; d < 2; ++d)
    for (int i = 0; i < 2; ++i){
      push(ppiw[d] + (size_t)i*512*2048, w_piw[d][i], 512, 512, 2048, 1);
      push(ppow[d] + (size_t)i*1024*512, w_pow[d][i], 1024, 1024, 512, 0);
    }
  for (int i = 0; i < 2; ++i){
    push(mrg_w  + (size_t)i*1024*512, w_mrg[i],  1024, 1024, 512, 0);
    push(ffn_w1 + (size_t)i*512*2048, w_ffn1[i], 512, 512, 2048, 0);
    push(ffn_w2 + (size_t)i*2048*512, w_ffn2[i], 2048, 2048, 512, 0);
  }
  transpose_all<<<base, 256, 0, stream>>>(pk);

  // ---- spatial encoding ----
  stats_enc<<<MROWS, 256, 0, stream>>>(attn, enc);
  // s += gelu(enc@W1+b1)@W2 + b2
  gemm_bt<0,64><<<dim3(4, 128), 256, 0, stream>>>(enc, w_sew1, w_sew1, se_b1, se_b1,
      nullptr, nullptr, t1h2, nullptr, 192, 512, 512);
  gemm_bt<1,64><<<dim3(4, 128), 256, 0, stream>>>(t1h2, w_sew2, w_sew2, se_b2, se_b2,
      s_in, sc, nullptr, nullptr, 512, 512, 512);

  // ---- layers (order/rv/flip cancel: all per-token) ----
  for (int i = 0; i < 2; ++i){
    ln_dual<<<MROWS/4, 256, 0, stream>>>(sc, png[0]+i*512, pnb[0]+i*512,
        png[1]+i*512, pnb[1]+i*512, hcat, hcat + (size_t)MROWS*512);
    // stacked f/b: zi + silu*sigmoid   [16384,512] @ [512,2048] -> u [16384][1024]
    gemm_bt<3,128><<<dim3(16, 128), 256, 0, stream>>>(hcat,
        w_piw[0][i], w_piw[1][i], ppib[0]+(size_t)i*2048, ppib[1]+(size_t)i*2048,
        nullptr, nullptr, upre, nullptr, 512, 2048, 1024);
    ln1024<<<(2*MROWS)/4, 256, 0, stream>>>(upre,
        pig[0]+i*1024, pibt[0]+i*1024, pig[1]+i*1024, pibt[1]+i*1024, ubf);
    // stacked f/b: u @ pow + sc -> fbuf (f cols 0-511, b cols 512-1023)
    gemm_bt<4,64><<<dim3(4, 256), 256, 0, stream>>>(ubf,
        w_pow[0][i], w_pow[1][i], ppob[0]+i*512, ppob[1]+i*512,
        sc, nullptr, fbuf, nullptr, 1024, 512, 1024);
    // merge: fbuf @ mrg + sc -> r2 (bf16)
    gemm_bt<4,64><<<dim3(4, 128), 256, 0, stream>>>(fbuf,
        w_mrg[i], w_mrg[i], mrg_b+i*512, mrg_b+i*512,
        sc, nullptr, r2, nullptr, 1024, 512, 512);
    ln_double<<<MROWS/4, 256, 0, stream>>>(r2, nrm_g+i*512, nrm_b+i*512,
        ffn_ng+i*512, ffn_nb+i*512, s1, t1h2);
    gemm_bt<0,128><<<dim3(16, 64), 256, 0, stream>>>(t1h2,
        w_ffn1[i], w_ffn1[i], ffn_b1+i*2048, ffn_b1+i*2048,
        nullptr, nullptr, t2, nullptr, 512, 2048, 2048);
    gemm_bt<2,64><<<dim3(4, 128), 256, 0, stream>>>(t2,
        w_ffn2[i], w_ffn2[i], ffn_b2+i*512, ffn_b2+i*512,
        s1, (i == 1 ? out : sc), nullptr, km, 2048, 512, 512);
  }
}